// Round 14
// baseline (321.909 us; speedup 1.0000x reference)
//
#include <hip/hip_runtime.h>
#include <hip/hip_fp16.h>

#define NN 100000
#define NE 1600000
#define D 128
#define NC 8
#define BNODES 2048  // nodes per bucket (2^11)
#define NBUCK 49     // ceil(NN / BNODES)
#define BCAP 36864   // bucket capacity; mean 32768, sigma ~180 -> +22 sigma margin
#define CHUNK 4096   // edges per scatter block
#define NBLK_SC ((NE + CHUNK - 1) / CHUNK)  // 391

typedef _Float16 half8 __attribute__((ext_vector_type(8)));
typedef float f32x4 __attribute__((ext_vector_type(4)));

// ---------------- K1: bucket scatter (blocks 0..390) + weight cvt (391,392) ------
// staged[b*BCAP + pos] = (src << 11) | (dst & 2047); bucket = dst >> 11.
// 49 buckets -> ~84 edges/bucket/block -> ~334B contiguous write runs (full lines).
__global__ __launch_bounds__(256) void k_scat(const int* __restrict__ src,
                                              const int* __restrict__ dst,
                                              int* __restrict__ bcursor,
                                              int* __restrict__ staged,
                                              const float* __restrict__ W1,
                                              __half* __restrict__ wt1,
                                              const float* __restrict__ W2,
                                              __half* __restrict__ wt2, int E) {
    const int t = threadIdx.x;
    if (blockIdx.x >= NBLK_SC) {  // wt[col][k] = half(W[k][col])
        const float* W = (blockIdx.x - NBLK_SC) ? W2 : W1;
        __half* wt = (blockIdx.x - NBLK_SC) ? wt2 : wt1;
        for (int i = t; i < D * D; i += 256) {
            int k = i >> 7, c = i & 127;
            wt[c * D + k] = __float2half(W[i]);
        }
        return;
    }
    __shared__ int h[NBUCK];
    __shared__ int cur[NBUCK];
    if (t < NBUCK) h[t] = 0;
    __syncthreads();
    const int base0 = blockIdx.x * CHUNK;
    int4 d4[4], s4[4];
    bool val[4];
#pragma unroll
    for (int i = 0; i < 4; ++i) {
        int e = base0 + i * 1024 + t * 4;
        val[i] = e < E;  // E % 4 == 0 -> full int4 safe
        if (val[i]) {
            d4[i] = *(const int4*)&dst[e];
            s4[i] = *(const int4*)&src[e];
            atomicAdd(&h[d4[i].x >> 11], 1);
            atomicAdd(&h[d4[i].y >> 11], 1);
            atomicAdd(&h[d4[i].z >> 11], 1);
            atomicAdd(&h[d4[i].w >> 11], 1);
        }
    }
    __syncthreads();
    if (t < NBUCK) {
        int c = h[t];
        cur[t] = c ? (t * BCAP + atomicAdd(&bcursor[t], c)) : 0;
    }
    __syncthreads();
#pragma unroll
    for (int i = 0; i < 4; ++i) {
        if (val[i]) {
            int p;
            p = atomicAdd(&cur[d4[i].x >> 11], 1); staged[p] = (s4[i].x << 11) | (d4[i].x & 2047);
            p = atomicAdd(&cur[d4[i].y >> 11], 1); staged[p] = (s4[i].y << 11) | (d4[i].y & 2047);
            p = atomicAdd(&cur[d4[i].z >> 11], 1); staged[p] = (s4[i].z << 11) | (d4[i].z & 2047);
            p = atomicAdd(&cur[d4[i].w >> 11], 1); staged[p] = (s4[i].w << 11) | (d4[i].w & 2047);
        }
    }
}

// ---------------- K2: per-bucket CSR build (49 blocks, 2048 nodes each) ----------
// LDS histogram over 2048 node slots -> 8-per-thread + block scan -> fill.
// Emits rowstart (absolute), cnt, dinv.
__global__ __launch_bounds__(256) void k_bfill(const int* __restrict__ staged,
                                               const int* __restrict__ bcursor,
                                               int* __restrict__ rowstart,
                                               int* __restrict__ cnt,
                                               float* __restrict__ dinv,
                                               int* __restrict__ csr) {
    const int b = blockIdx.x;
    const int t = threadIdx.x;
    const int bs = b * BCAP;
    const int be = bs + bcursor[b];
    __shared__ int lc[BNODES];  // per-node count, later reused as cursor
    __shared__ int ls[BNODES];  // per-node absolute csr start
    __shared__ int sd[256];     // block-scan temp
#pragma unroll
    for (int j = 0; j < 8; ++j) lc[t + j * 256] = 0;
    __syncthreads();
    for (int i = bs + t; i < be; i += 256)
        atomicAdd(&lc[staged[i] & (BNODES - 1)], 1);
    __syncthreads();
    // scan: thread t owns lc[t*8 .. t*8+7]
    int loc[8];
    int s = 0;
#pragma unroll
    for (int j = 0; j < 8; ++j) { loc[j] = s; s += lc[t * 8 + j]; }
    sd[t] = s;
    __syncthreads();
    for (int off = 1; off < 256; off <<= 1) {
        int y = (t >= off) ? sd[t - off] : 0;
        __syncthreads();
        sd[t] += y;
        __syncthreads();
    }
    int base = sd[t] - s;  // exclusive prefix of this thread's 8-chunk
#pragma unroll
    for (int j = 0; j < 8; ++j) ls[t * 8 + j] = bs + base + loc[j];
    __syncthreads();
    // emit rowstart/cnt/dinv (coalesced, stride-256 loop)
    const int node0 = b * BNODES;
    for (int idx = t; idx < BNODES; idx += 256) {
        int node = node0 + idx;
        if (node < NN) {
            int c = lc[idx];
            rowstart[node] = ls[idx];
            cnt[node] = c;
            dinv[node] = rsqrtf((float)(c + 1));  // +1 = self-loop
        }
    }
    // reuse lc as per-node cursor
#pragma unroll
    for (int j = 0; j < 8; ++j) lc[t + j * 256] = 0;
    __syncthreads();
    for (int i = bs + t; i < be; i += 256) {
        int e = staged[i];
        int li = e & (BNODES - 1);
        int p = atomicAdd(&lc[li], 1);
        csr[ls[li] + p] = e >> 11;
    }
}

// ---------------- gemm: hout[r] = half((A[r] @ W) * dinv[r]) ---------------------
// 4 waves/block; wave = 16 rows x 64 cols (4 col-tiles x 4 K-steps of 16x16x32).
template <bool F32IN>
__global__ __launch_bounds__(256) void k_gemm(const void* __restrict__ Ain,
                                              const __half* __restrict__ wt,
                                              const float* __restrict__ dinv,
                                              __half* __restrict__ hout) {
    const int tid = threadIdx.x;
    const int lane = tid & 63;
    const int wave = tid >> 6;
    const int wr = wave >> 1, wc = wave & 1;
    const int row0 = blockIdx.x * 32 + wr * 16;
    const int arow = row0 + (lane & 15);
    const int kg = lane >> 4;

    half8 afrag[4];
    if constexpr (F32IN) {
        const float* A = (const float*)Ain;
#pragma unroll
        for (int s = 0; s < 4; ++s) {
            const float* p = &A[(size_t)arow * D + s * 32 + kg * 8];
            float4 f0 = *(const float4*)p;
            float4 f1 = *(const float4*)(p + 4);
            half8 a;
            a[0] = (_Float16)f0.x; a[1] = (_Float16)f0.y;
            a[2] = (_Float16)f0.z; a[3] = (_Float16)f0.w;
            a[4] = (_Float16)f1.x; a[5] = (_Float16)f1.y;
            a[6] = (_Float16)f1.z; a[7] = (_Float16)f1.w;
            afrag[s] = a;
        }
    } else {
        const __half* A = (const __half*)Ain;
#pragma unroll
        for (int s = 0; s < 4; ++s)
            afrag[s] = *(const half8*)&A[(size_t)arow * D + s * 32 + kg * 8];
    }

    f32x4 acc[4] = {};
    const int colbase = wc * 64;
#pragma unroll
    for (int c = 0; c < 4; ++c) {
        const int col = colbase + c * 16 + (lane & 15);
#pragma unroll
        for (int s = 0; s < 4; ++s) {
            half8 b = *(const half8*)&wt[col * D + s * 32 + kg * 8];
            acc[c] = __builtin_amdgcn_mfma_f32_16x16x32_f16(afrag[s], b, acc[c], 0, 0, 0);
        }
    }

#pragma unroll
    for (int r = 0; r < 4; ++r) {
        const int row = row0 + kg * 4 + r;
        const float dv = dinv[row];
#pragma unroll
        for (int c = 0; c < 4; ++c) {
            const int col = colbase + c * 16 + (lane & 15);
            hout[(size_t)row * D + col] = __float2half(acc[c][r] * dv);
        }
    }
}

__device__ inline void add8h(float* acc, float4 raw) {
    const __half2* hp = (const __half2*)&raw;
#pragma unroll
    for (int q = 0; q < 4; ++q) {
        float2 f = __half22float2(hp[q]);
        acc[2 * q] += f.x;
        acc[2 * q + 1] += f.y;
    }
}

// ---------------- aggregation (cheap variant, r10-proven 67.5us) -----------------
// h is pre-scaled by dinv[row]; gather+add, final scale dinv[node], bias, relu.
// 16 lanes x 16B cover a row; 4 groups; prefetch 8 rows/pass (32 in flight/wave).
__global__ __launch_bounds__(256) void k_agg(const __half* __restrict__ hs,
                                             const int* __restrict__ rowstart,
                                             const int* __restrict__ cnt,
                                             const int* __restrict__ csr_src,
                                             const float* __restrict__ dinv,
                                             const float* __restrict__ bias,
                                             __half* __restrict__ hout) {
    const int node = blockIdx.x * 4 + (threadIdx.x >> 6);  // NN % 4 == 0, exact grid
    const int lane = threadIdx.x & 63;
    const int g = lane >> 4;           // neighbor group 0..3
    const int f8 = (lane & 15) << 3;   // feature offset (8 halves = 16B per lane)

    float acc[8] = {};
    if (g == 0) add8h(acc, *(const float4*)&hs[(size_t)node * D + f8]);  // self-loop

    const int c = cnt[node];
    const int* __restrict__ cl = csr_src + rowstart[node];

    int t = g;
    while (t < c) {
        float4 v[8];
#pragma unroll
        for (int i = 0; i < 8; ++i) {
            int tt = t + 4 * i;
            if (tt < c) {
                int s = cl[tt];
                v[i] = *(const float4*)&hs[(size_t)s * D + f8];
            }
        }
#pragma unroll
        for (int i = 0; i < 8; ++i) {
            int tt = t + 4 * i;
            if (tt < c) add8h(acc, v[i]);
        }
        t += 32;
    }

#pragma unroll
    for (int q = 0; q < 8; ++q) {
        acc[q] += __shfl_xor(acc[q], 16);
        acc[q] += __shfl_xor(acc[q], 32);
    }

    if (g == 0) {
        const float dv = dinv[node];
        float r[8];
#pragma unroll
        for (int q = 0; q < 8; ++q) r[q] = fmaxf(fmaf(dv, acc[q], bias[f8 + q]), 0.f);
        union { float4 f; __half2 h[4]; } u;
#pragma unroll
        for (int q = 0; q < 4; ++q) u.h[q] = __floats2half2_rn(r[2 * q], r[2 * q + 1]);
        *(float4*)&hout[(size_t)node * D + f8] = u.f;
    }
}

// ---------------- output: softmax(h @ Wout + bout), fp16 h ----------------
__global__ void k_out(const __half* __restrict__ h, const float* __restrict__ Wout,
                      const float* __restrict__ bout, float* __restrict__ out, int n) {
    __shared__ float ws[D * NC];
    int tid = threadIdx.x;
    for (int i = tid; i < D * NC; i += 256) ws[i] = Wout[i];
    __syncthreads();
    int node = blockIdx.x * 32 + (tid >> 3);
    int c = tid & 7;
    if (node >= n) return;
    float acc = bout[c];
    const __half* hrow = &h[(size_t)node * D];
#pragma unroll
    for (int k8 = 0; k8 < 16; ++k8) {
        float4 raw = *(const float4*)&hrow[k8 * 8];
        const __half2* hp = (const __half2*)&raw;
#pragma unroll
        for (int q = 0; q < 4; ++q) {
            float2 f = __half22float2(hp[q]);
            int k = k8 * 8 + 2 * q;
            acc += f.x * ws[k * NC + c] + f.y * ws[(k + 1) * NC + c];
        }
    }
    float m = acc;
#pragma unroll
    for (int off = 1; off < 8; off <<= 1) m = fmaxf(m, __shfl_xor(m, off));
    float e = __expf(acc - m);
    float ssum = e;
#pragma unroll
    for (int off = 1; off < 8; off <<= 1) ssum += __shfl_xor(ssum, off);
    out[(size_t)node * NC + c] = e / ssum;
}

// ---------------- launch ----------------
extern "C" void kernel_launch(void* const* d_in, const int* in_sizes, int n_in,
                              void* d_out, int out_size, void* d_ws, size_t ws_size,
                              hipStream_t stream) {
    const float* x    = (const float*)d_in[0];
    const int*   ei   = (const int*)d_in[1];   // [2][NE]: row 0 = src, row 1 = dst
    const float* W1   = (const float*)d_in[2];
    const float* b1   = (const float*)d_in[3];
    const float* W2   = (const float*)d_in[4];
    const float* b2   = (const float*)d_in[5];
    const float* Wout = (const float*)d_in[6];
    const float* bout = (const float*)d_in[7];
    float* out = (float*)d_out;

    size_t off = 0;
    char* base = (char*)d_ws;
    auto alloc = [&](size_t bytes) -> void* {
        void* p = base + off;
        off += (bytes + 255) & ~(size_t)255;
        return p;
    };
    int*    cnt      = (int*)alloc((size_t)NN * 4);
    int*    rowstart = (int*)alloc((size_t)NN * 4);
    int*    bcursor  = (int*)alloc((size_t)NBUCK * 4);
    int*    csr      = (int*)alloc((size_t)NBUCK * BCAP * 4);  // bucket-padded
    float*  dinv     = (float*)alloc((size_t)NN * 4);
    __half* wt1      = (__half*)alloc((size_t)D * D * 2);
    __half* wt2      = (__half*)alloc((size_t)D * D * 2);
    __half* h16a     = (__half*)alloc((size_t)NN * D * 2);
    __half* h16f     = (__half*)alloc((size_t)NN * D * 2);
    __half* h16b     = (__half*)alloc((size_t)NN * D * 2);
    int*    staged   = (int*)alloc((size_t)NBUCK * BCAP * 4);
    if (off > ws_size) return;  // workspace too small; fail visibly

    const int* src = ei;
    const int* dst = ei + NE;

    hipMemsetAsync(bcursor, 0, (size_t)NBUCK * 4, stream);

    // K1: bucket scatter (391 blocks) + weight cvt (2 blocks)
    k_scat<<<NBLK_SC + 2, 256, 0, stream>>>(src, dst, bcursor, staged,
                                            W1, wt1, W2, wt2, NE);
    // K2: per-bucket CSR build (49 blocks) -> rowstart/cnt/dinv/csr
    k_bfill<<<NBUCK, 256, 0, stream>>>(staged, bcursor, rowstart, cnt, dinv, csr);

    int gemm_grid = NN / 32;   // 3125 exactly
    int agg_grid = NN / 4;     // 25000 exactly
    // layer 1: scaled gemm -> cheap agg
    k_gemm<true><<<gemm_grid, 256, 0, stream>>>(x, wt1, dinv, h16a);
    k_agg<<<agg_grid, 256, 0, stream>>>(h16a, rowstart, cnt, csr, dinv, b1, h16f);
    // layer 2: scaled gemm -> cheap agg
    k_gemm<false><<<gemm_grid, 256, 0, stream>>>(h16f, wt2, dinv, h16a);
    k_agg<<<agg_grid, 256, 0, stream>>>(h16a, rowstart, cnt, csr, dinv, b2, h16b);
    // output projection + softmax
    k_out<<<(NN + 31) / 32, 256, 0, stream>>>(h16b, Wout, bout, out, NN);
}

// Round 15
// 272.284 us; speedup vs baseline: 1.1823x; 1.1823x over previous
//
#include <hip/hip_runtime.h>
#include <hip/hip_fp16.h>

#define NN 100000
#define NE 1600000
#define D 128
#define NC 8
#define NBUCK 391   // ceil(NN / 256) buckets of 256 node-ids
#define BCAP 6144   // fixed bucket capacity (mean 4092 -> huge margin)
#define CHUNK 4096  // edges per scatter block
#define NBLK_SC ((NE + CHUNK - 1) / CHUNK)  // 391

typedef _Float16 half8 __attribute__((ext_vector_type(8)));
typedef float f32x4 __attribute__((ext_vector_type(4)));

// ---------------- K1: bucket scatter (blocks 0..390) + weight cvt (391,392) ------
// staged[b*BCAP + pos] = src*256 | (dst&255)  (r10/r13-proven)
__global__ __launch_bounds__(256) void k_scat(const int* __restrict__ src,
                                              const int* __restrict__ dst,
                                              int* __restrict__ bcursor,
                                              int* __restrict__ staged,
                                              const float* __restrict__ W1,
                                              __half* __restrict__ wt1,
                                              const float* __restrict__ W2,
                                              __half* __restrict__ wt2, int E) {
    const int t = threadIdx.x;
    if (blockIdx.x >= NBLK_SC) {  // wt[col][k] = half(W[k][col])
        const float* W = (blockIdx.x - NBLK_SC) ? W2 : W1;
        __half* wt = (blockIdx.x - NBLK_SC) ? wt2 : wt1;
        for (int i = t; i < D * D; i += 256) {
            int k = i >> 7, c = i & 127;
            wt[c * D + k] = __float2half(W[i]);
        }
        return;
    }
    __shared__ int h[NBUCK];
    __shared__ int cur[NBUCK];
    for (int i = t; i < NBUCK; i += 256) h[i] = 0;
    __syncthreads();
    const int base0 = blockIdx.x * CHUNK;
    int4 d4[4], s4[4];
    bool val[4];
#pragma unroll
    for (int i = 0; i < 4; ++i) {
        int e = base0 + i * 1024 + t * 4;
        val[i] = e < E;  // E % 4 == 0 -> full int4 safe
        if (val[i]) {
            d4[i] = *(const int4*)&dst[e];
            s4[i] = *(const int4*)&src[e];
            atomicAdd(&h[d4[i].x >> 8], 1);
            atomicAdd(&h[d4[i].y >> 8], 1);
            atomicAdd(&h[d4[i].z >> 8], 1);
            atomicAdd(&h[d4[i].w >> 8], 1);
        }
    }
    __syncthreads();
    for (int i = t; i < NBUCK; i += 256) {
        int c = h[i];
        cur[i] = c ? (i * BCAP + atomicAdd(&bcursor[i], c)) : 0;
    }
    __syncthreads();
#pragma unroll
    for (int i = 0; i < 4; ++i) {
        if (val[i]) {
            int p;
            p = atomicAdd(&cur[d4[i].x >> 8], 1); staged[p] = s4[i].x * 256 + (d4[i].x & 255);
            p = atomicAdd(&cur[d4[i].y >> 8], 1); staged[p] = s4[i].y * 256 + (d4[i].y & 255);
            p = atomicAdd(&cur[d4[i].z >> 8], 1); staged[p] = s4[i].z * 256 + (d4[i].z & 255);
            p = atomicAdd(&cur[d4[i].w >> 8], 1); staged[p] = s4[i].w * 256 + (d4[i].w & 255);
        }
    }
}

// ---------------- K2: per-bucket CSR build (391 blocks; r10-proven) ---------------
__global__ __launch_bounds__(256) void k_bfill(const int* __restrict__ staged,
                                               const int* __restrict__ bcursor,
                                               int* __restrict__ rowstart,
                                               int* __restrict__ cnt,
                                               float* __restrict__ dinv,
                                               int* __restrict__ csr) {
    const int b = blockIdx.x;
    const int t = threadIdx.x;
    const int bs = b * BCAP;
    const int be = bs + bcursor[b];
    __shared__ int lc[256];
    __shared__ int ls[256];
    __shared__ int sd[256];
    lc[t] = 0;
    __syncthreads();
    for (int i = bs + t; i < be; i += 256) {
        atomicAdd(&lc[staged[i] & 255], 1);
    }
    __syncthreads();
    int v = lc[t];
    sd[t] = v;
    __syncthreads();
    for (int off = 1; off < 256; off <<= 1) {
        int y = (t >= off) ? sd[t - off] : 0;
        __syncthreads();
        sd[t] += y;
        __syncthreads();
    }
    int ex = sd[t] - v;
    ls[t] = bs + ex;
    int node = (b << 8) + t;
    if (node < NN) {
        rowstart[node] = bs + ex;
        cnt[node] = v;
        dinv[node] = rsqrtf((float)(v + 1));  // +1 = self-loop
    }
    lc[t] = 0;
    __syncthreads();
    for (int i = bs + t; i < be; i += 256) {
        int e = staged[i];
        int li = e & 255;
        int p = atomicAdd(&lc[li], 1);
        csr[ls[li] + p] = e >> 8;
    }
}

// ---------------- gemm layer 1: hout[r] = half((x[r] @ W1) * dinv[r]) ------------
__global__ __launch_bounds__(256) void k_gemm1(const float* __restrict__ A,
                                               const __half* __restrict__ wt,
                                               const float* __restrict__ dinv,
                                               __half* __restrict__ hout) {
    const int tid = threadIdx.x;
    const int lane = tid & 63;
    const int wave = tid >> 6;
    const int wr = wave >> 1, wc = wave & 1;
    const int row0 = blockIdx.x * 32 + wr * 16;
    const int arow = row0 + (lane & 15);
    const int kg = lane >> 4;

    half8 afrag[4];
#pragma unroll
    for (int s = 0; s < 4; ++s) {
        const float* p = &A[(size_t)arow * D + s * 32 + kg * 8];
        float4 f0 = *(const float4*)p;
        float4 f1 = *(const float4*)(p + 4);
        half8 a;
        a[0] = (_Float16)f0.x; a[1] = (_Float16)f0.y;
        a[2] = (_Float16)f0.z; a[3] = (_Float16)f0.w;
        a[4] = (_Float16)f1.x; a[5] = (_Float16)f1.y;
        a[6] = (_Float16)f1.z; a[7] = (_Float16)f1.w;
        afrag[s] = a;
    }

    f32x4 acc[4] = {};
    const int colbase = wc * 64;
#pragma unroll
    for (int c = 0; c < 4; ++c) {
        const int col = colbase + c * 16 + (lane & 15);
#pragma unroll
        for (int s = 0; s < 4; ++s) {
            half8 b = *(const half8*)&wt[col * D + s * 32 + kg * 8];
            acc[c] = __builtin_amdgcn_mfma_f32_16x16x32_f16(afrag[s], b, acc[c], 0, 0, 0);
        }
    }

#pragma unroll
    for (int r = 0; r < 4; ++r) {
        const int row = row0 + kg * 4 + r;
        const float dv = dinv[row];
#pragma unroll
        for (int c = 0; c < 4; ++c) {
            const int col = colbase + c * 16 + (lane & 15);
            hout[(size_t)row * D + col] = __float2half(acc[c][r] * dv);
        }
    }
}

__device__ inline void add8h(float* acc, float4 raw) {
    const __half2* hp = (const __half2*)&raw;
#pragma unroll
    for (int q = 0; q < 4; ++q) {
        float2 f = __half22float2(hp[q]);
        acc[2 * q] += f.x;
        acc[2 * q + 1] += f.y;
    }
}

// ---------------- FUSED agg1 + gemm2 ---------------------------------------------
// Block = 16 nodes. Phase A: wave w aggregates nodes w*4..w*4+3 serially (cheap agg:
// h pre-scaled, 32 rows in flight/wave during each node) -> relu rows into padded
// LDS tile [16][136]. Phase B: 4 waves MFMA the 16x128 tile @ wt2; wave w owns cols
// [w*32, w*32+32); epilogue scales by dinv[row] -> hout (pre-scaled for agg2).
// Saves the 51 MB h16f write+read round-trip of separate agg1/gemm2.
__global__ __launch_bounds__(256) void k_aggemm(const __half* __restrict__ hs,
                                                const int* __restrict__ rowstart,
                                                const int* __restrict__ cnt,
                                                const int* __restrict__ csr_src,
                                                const float* __restrict__ dinv,
                                                const float* __restrict__ b1,
                                                const __half* __restrict__ wt2,
                                                __half* __restrict__ hout) {
    __shared__ __align__(16) __half rows[16][136];  // +8 pad: 272B row stride
    const int w = threadIdx.x >> 6;
    const int lane = threadIdx.x & 63;
    const int g = lane >> 4;
    const int f8 = (lane & 15) << 3;
    const int nb = blockIdx.x * 16;  // NN % 16 == 0 -> exact

    // ---- Phase A: aggregate 4 nodes per wave ----
    for (int k = 0; k < 4; ++k) {
        const int node = nb + w * 4 + k;
        float acc[8] = {};
        if (g == 0) add8h(acc, *(const float4*)&hs[(size_t)node * D + f8]);  // self
        const int c = cnt[node];
        const int* __restrict__ cl = csr_src + rowstart[node];
        int t = g;
        while (t < c) {
            float4 v[8];
#pragma unroll
            for (int i = 0; i < 8; ++i) {
                int tt = t + 4 * i;
                if (tt < c) v[i] = *(const float4*)&hs[(size_t)cl[tt] * D + f8];
            }
#pragma unroll
            for (int i = 0; i < 8; ++i) {
                int tt = t + 4 * i;
                if (tt < c) add8h(acc, v[i]);
            }
            t += 32;
        }
#pragma unroll
        for (int q = 0; q < 8; ++q) {
            acc[q] += __shfl_xor(acc[q], 16);
            acc[q] += __shfl_xor(acc[q], 32);
        }
        if (g == 0) {
            const float dv = dinv[node];
            union { float4 f; __half2 h2[4]; } u;
#pragma unroll
            for (int q = 0; q < 4; ++q) {
                float r0 = fmaxf(fmaf(dv, acc[2 * q], b1[f8 + 2 * q]), 0.f);
                float r1 = fmaxf(fmaf(dv, acc[2 * q + 1], b1[f8 + 2 * q + 1]), 0.f);
                u.h2[q] = __floats2half2_rn(r0, r1);
            }
            *(float4*)&rows[w * 4 + k][f8] = u.f;
        }
    }
    __syncthreads();

    // ---- Phase B: 16x128 tile @ wt2 ----
    const int kg = lane >> 4;
    const int l15 = lane & 15;
    half8 afrag[4];
#pragma unroll
    for (int s = 0; s < 4; ++s)
        afrag[s] = *(const half8*)&rows[l15][s * 32 + kg * 8];
    f32x4 acc2[2] = {};
#pragma unroll
    for (int ct = 0; ct < 2; ++ct) {
        const int col = w * 32 + ct * 16 + l15;
#pragma unroll
        for (int s = 0; s < 4; ++s) {
            half8 b = *(const half8*)&wt2[col * D + s * 32 + kg * 8];
            acc2[ct] = __builtin_amdgcn_mfma_f32_16x16x32_f16(afrag[s], b, acc2[ct], 0, 0, 0);
        }
    }
#pragma unroll
    for (int r = 0; r < 4; ++r) {
        const int row = nb + kg * 4 + r;
        const float dv = dinv[row];
#pragma unroll
        for (int ct = 0; ct < 2; ++ct) {
            const int col = w * 32 + ct * 16 + l15;
            hout[(size_t)row * D + col] = __float2half(acc2[ct][r] * dv);
        }
    }
}

// ---------------- agg layer 2 (cheap variant; r10-proven 67.5us) -----------------
__global__ __launch_bounds__(256) void k_agg(const __half* __restrict__ hs,
                                             const int* __restrict__ rowstart,
                                             const int* __restrict__ cnt,
                                             const int* __restrict__ csr_src,
                                             const float* __restrict__ dinv,
                                             const float* __restrict__ bias,
                                             __half* __restrict__ hout) {
    const int node = blockIdx.x * 4 + (threadIdx.x >> 6);
    const int lane = threadIdx.x & 63;
    const int g = lane >> 4;
    const int f8 = (lane & 15) << 3;

    float acc[8] = {};
    if (g == 0) add8h(acc, *(const float4*)&hs[(size_t)node * D + f8]);

    const int c = cnt[node];
    const int* __restrict__ cl = csr_src + rowstart[node];

    int t = g;
    while (t < c) {
        float4 v[8];
#pragma unroll
        for (int i = 0; i < 8; ++i) {
            int tt = t + 4 * i;
            if (tt < c) {
                int s = cl[tt];
                v[i] = *(const float4*)&hs[(size_t)s * D + f8];
            }
        }
#pragma unroll
        for (int i = 0; i < 8; ++i) {
            int tt = t + 4 * i;
            if (tt < c) add8h(acc, v[i]);
        }
        t += 32;
    }

#pragma unroll
    for (int q = 0; q < 8; ++q) {
        acc[q] += __shfl_xor(acc[q], 16);
        acc[q] += __shfl_xor(acc[q], 32);
    }

    if (g == 0) {
        const float dv = dinv[node];
        float r[8];
#pragma unroll
        for (int q = 0; q < 8; ++q) r[q] = fmaxf(fmaf(dv, acc[q], bias[f8 + q]), 0.f);
        union { float4 f; __half2 h[4]; } u;
#pragma unroll
        for (int q = 0; q < 4; ++q) u.h[q] = __floats2half2_rn(r[2 * q], r[2 * q + 1]);
        *(float4*)&hout[(size_t)node * D + f8] = u.f;
    }
}

// ---------------- output: softmax(h @ Wout + bout), fp16 h ----------------
__global__ void k_out(const __half* __restrict__ h, const float* __restrict__ Wout,
                      const float* __restrict__ bout, float* __restrict__ out, int n) {
    __shared__ float ws[D * NC];
    int tid = threadIdx.x;
    for (int i = tid; i < D * NC; i += 256) ws[i] = Wout[i];
    __syncthreads();
    int node = blockIdx.x * 32 + (tid >> 3);
    int c = tid & 7;
    if (node >= n) return;
    float acc = bout[c];
    const __half* hrow = &h[(size_t)node * D];
#pragma unroll
    for (int k8 = 0; k8 < 16; ++k8) {
        float4 raw = *(const float4*)&hrow[k8 * 8];
        const __half2* hp = (const __half2*)&raw;
#pragma unroll
        for (int q = 0; q < 4; ++q) {
            float2 f = __half22float2(hp[q]);
            int k = k8 * 8 + 2 * q;
            acc += f.x * ws[k * NC + c] + f.y * ws[(k + 1) * NC + c];
        }
    }
    float m = acc;
#pragma unroll
    for (int off = 1; off < 8; off <<= 1) m = fmaxf(m, __shfl_xor(m, off));
    float e = __expf(acc - m);
    float ssum = e;
#pragma unroll
    for (int off = 1; off < 8; off <<= 1) ssum += __shfl_xor(ssum, off);
    out[(size_t)node * NC + c] = e / ssum;
}

// ---------------- launch ----------------
extern "C" void kernel_launch(void* const* d_in, const int* in_sizes, int n_in,
                              void* d_out, int out_size, void* d_ws, size_t ws_size,
                              hipStream_t stream) {
    const float* x    = (const float*)d_in[0];
    const int*   ei   = (const int*)d_in[1];   // [2][NE]: row 0 = src, row 1 = dst
    const float* W1   = (const float*)d_in[2];
    const float* b1   = (const float*)d_in[3];
    const float* W2   = (const float*)d_in[4];
    const float* b2   = (const float*)d_in[5];
    const float* Wout = (const float*)d_in[6];
    const float* bout = (const float*)d_in[7];
    float* out = (float*)d_out;

    size_t off = 0;
    char* base = (char*)d_ws;
    auto alloc = [&](size_t bytes) -> void* {
        void* p = base + off;
        off += (bytes + 255) & ~(size_t)255;
        return p;
    };
    int*    cnt      = (int*)alloc((size_t)NN * 4);
    int*    rowstart = (int*)alloc((size_t)NN * 4);
    int*    bcursor  = (int*)alloc((size_t)NBUCK * 4);
    int*    csr      = (int*)alloc((size_t)NBUCK * BCAP * 4);  // bucket-padded
    float*  dinv     = (float*)alloc((size_t)NN * 4);
    __half* wt1      = (__half*)alloc((size_t)D * D * 2);
    __half* wt2      = (__half*)alloc((size_t)D * D * 2);
    __half* h16a     = (__half*)alloc((size_t)NN * D * 2);  // gemm1 out / aggemm in
    __half* h16g     = (__half*)alloc((size_t)NN * D * 2);  // aggemm out (pre-scaled)
    __half* h16b     = (__half*)alloc((size_t)NN * D * 2);  // agg2 out
    int*    staged   = (int*)alloc((size_t)NBUCK * BCAP * 4);
    if (off > ws_size) return;  // workspace too small; fail visibly

    const int* src = ei;
    const int* dst = ei + NE;

    hipMemsetAsync(bcursor, 0, (size_t)NBUCK * 4, stream);

    // K1: bucket scatter (391 blocks) + weight cvt (2 blocks)
    k_scat<<<NBLK_SC + 2, 256, 0, stream>>>(src, dst, bcursor, staged,
                                            W1, wt1, W2, wt2, NE);
    // K2: per-bucket CSR build
    k_bfill<<<NBUCK, 256, 0, stream>>>(staged, bcursor, rowstart, cnt, dinv, csr);

    // layer 1 gemm (dinv-scaled)
    k_gemm1<<<NN / 32, 256, 0, stream>>>(x, wt1, dinv, h16a);
    // FUSED: agg1 + gemm2 (dinv-scaled epilogue)
    k_aggemm<<<NN / 16, 256, 0, stream>>>(h16a, rowstart, cnt, csr, dinv, b1,
                                          wt2, h16g);
    // layer 2 aggregation (cheap)
    k_agg<<<NN / 4, 256, 0, stream>>>(h16g, rowstart, cnt, csr, dinv, b2, h16b);
    // output projection + softmax
    k_out<<<(NN + 31) / 32, 256, 0, stream>>>(h16b, Wout, bout, out, NN);
}

// Round 16
// 271.303 us; speedup vs baseline: 1.1865x; 1.0036x over previous
//
#include <hip/hip_runtime.h>
#include <hip/hip_fp16.h>

#define NN 100000
#define NE 1600000
#define D 128
#define NC 8
#define NBUCK 391   // ceil(NN / 256) buckets of 256 node-ids
#define BCAP 6144   // fixed bucket capacity (mean 4092 -> huge margin)
#define CHUNK 4096  // edges per scatter block
#define NBLK_SC ((NE + CHUNK - 1) / CHUNK)  // 391

typedef _Float16 half8 __attribute__((ext_vector_type(8)));
typedef float f32x4 __attribute__((ext_vector_type(4)));

// ---------------- K1: bucket scatter (blocks 0..390) + weight cvt (391,392) ------
// staged[b*BCAP + pos] = src*256 | (dst&255)
__global__ __launch_bounds__(256) void k_scat(const int* __restrict__ src,
                                              const int* __restrict__ dst,
                                              int* __restrict__ bcursor,
                                              int* __restrict__ staged,
                                              const float* __restrict__ W1,
                                              __half* __restrict__ wt1,
                                              const float* __restrict__ W2,
                                              __half* __restrict__ wt2, int E) {
    const int t = threadIdx.x;
    if (blockIdx.x >= NBLK_SC) {  // wt[col][k] = half(W[k][col])
        const float* W = (blockIdx.x - NBLK_SC) ? W2 : W1;
        __half* wt = (blockIdx.x - NBLK_SC) ? wt2 : wt1;
        for (int i = t; i < D * D; i += 256) {
            int k = i >> 7, c = i & 127;
            wt[c * D + k] = __float2half(W[i]);
        }
        return;
    }
    __shared__ int h[NBUCK];
    __shared__ int cur[NBUCK];
    for (int i = t; i < NBUCK; i += 256) h[i] = 0;
    __syncthreads();
    const int base0 = blockIdx.x * CHUNK;
    int4 d4[4], s4[4];
    bool val[4];
#pragma unroll
    for (int i = 0; i < 4; ++i) {
        int e = base0 + i * 1024 + t * 4;
        val[i] = e < E;  // E % 4 == 0 -> full int4 safe
        if (val[i]) {
            d4[i] = *(const int4*)&dst[e];
            s4[i] = *(const int4*)&src[e];
            atomicAdd(&h[d4[i].x >> 8], 1);
            atomicAdd(&h[d4[i].y >> 8], 1);
            atomicAdd(&h[d4[i].z >> 8], 1);
            atomicAdd(&h[d4[i].w >> 8], 1);
        }
    }
    __syncthreads();
    for (int i = t; i < NBUCK; i += 256) {
        int c = h[i];
        cur[i] = c ? (i * BCAP + atomicAdd(&bcursor[i], c)) : 0;
    }
    __syncthreads();
#pragma unroll
    for (int i = 0; i < 4; ++i) {
        if (val[i]) {
            int p;
            p = atomicAdd(&cur[d4[i].x >> 8], 1); staged[p] = s4[i].x * 256 + (d4[i].x & 255);
            p = atomicAdd(&cur[d4[i].y >> 8], 1); staged[p] = s4[i].y * 256 + (d4[i].y & 255);
            p = atomicAdd(&cur[d4[i].z >> 8], 1); staged[p] = s4[i].z * 256 + (d4[i].z & 255);
            p = atomicAdd(&cur[d4[i].w >> 8], 1); staged[p] = s4[i].w * 256 + (d4[i].w & 255);
        }
    }
}

// ---------------- K2: per-bucket CSR build (391 blocks; r10-proven) ---------------
__global__ __launch_bounds__(256) void k_bfill(const int* __restrict__ staged,
                                               const int* __restrict__ bcursor,
                                               int* __restrict__ rowstart,
                                               int* __restrict__ cnt,
                                               float* __restrict__ dinv,
                                               int* __restrict__ csr) {
    const int b = blockIdx.x;
    const int t = threadIdx.x;
    const int bs = b * BCAP;
    const int be = bs + bcursor[b];
    __shared__ int lc[256];
    __shared__ int ls[256];
    __shared__ int sd[256];
    lc[t] = 0;
    __syncthreads();
    for (int i = bs + t; i < be; i += 256) {
        atomicAdd(&lc[staged[i] & 255], 1);
    }
    __syncthreads();
    int v = lc[t];
    sd[t] = v;
    __syncthreads();
    for (int off = 1; off < 256; off <<= 1) {
        int y = (t >= off) ? sd[t - off] : 0;
        __syncthreads();
        sd[t] += y;
        __syncthreads();
    }
    int ex = sd[t] - v;
    ls[t] = bs + ex;
    int node = (b << 8) + t;
    if (node < NN) {
        rowstart[node] = bs + ex;
        cnt[node] = v;
        dinv[node] = rsqrtf((float)(v + 1));  // +1 = self-loop
    }
    lc[t] = 0;
    __syncthreads();
    for (int i = bs + t; i < be; i += 256) {
        int e = staged[i];
        int li = e & 255;
        int p = atomicAdd(&lc[li], 1);
        csr[ls[li] + p] = e >> 8;
    }
}

// ---------------- gemm: hout[r] = half((A[r] @ W) * dinv[r]) ---------------------
// 4 waves/block; wave = 16 rows x 64 cols (4 col-tiles x 4 K-steps of 16x16x32).
template <bool F32IN>
__global__ __launch_bounds__(256) void k_gemm(const void* __restrict__ Ain,
                                              const __half* __restrict__ wt,
                                              const float* __restrict__ dinv,
                                              __half* __restrict__ hout) {
    const int tid = threadIdx.x;
    const int lane = tid & 63;
    const int wave = tid >> 6;
    const int wr = wave >> 1, wc = wave & 1;
    const int row0 = blockIdx.x * 32 + wr * 16;
    const int arow = row0 + (lane & 15);
    const int kg = lane >> 4;

    half8 afrag[4];
    if constexpr (F32IN) {
        const float* A = (const float*)Ain;
#pragma unroll
        for (int s = 0; s < 4; ++s) {
            const float* p = &A[(size_t)arow * D + s * 32 + kg * 8];
            float4 f0 = *(const float4*)p;
            float4 f1 = *(const float4*)(p + 4);
            half8 a;
            a[0] = (_Float16)f0.x; a[1] = (_Float16)f0.y;
            a[2] = (_Float16)f0.z; a[3] = (_Float16)f0.w;
            a[4] = (_Float16)f1.x; a[5] = (_Float16)f1.y;
            a[6] = (_Float16)f1.z; a[7] = (_Float16)f1.w;
            afrag[s] = a;
        }
    } else {
        const __half* A = (const __half*)Ain;
#pragma unroll
        for (int s = 0; s < 4; ++s)
            afrag[s] = *(const half8*)&A[(size_t)arow * D + s * 32 + kg * 8];
    }

    f32x4 acc[4] = {};
    const int colbase = wc * 64;
#pragma unroll
    for (int c = 0; c < 4; ++c) {
        const int col = colbase + c * 16 + (lane & 15);
#pragma unroll
        for (int s = 0; s < 4; ++s) {
            half8 b = *(const half8*)&wt[col * D + s * 32 + kg * 8];
            acc[c] = __builtin_amdgcn_mfma_f32_16x16x32_f16(afrag[s], b, acc[c], 0, 0, 0);
        }
    }

#pragma unroll
    for (int r = 0; r < 4; ++r) {
        const int row = row0 + kg * 4 + r;
        const float dv = dinv[row];
#pragma unroll
        for (int c = 0; c < 4; ++c) {
            const int col = colbase + c * 16 + (lane & 15);
            hout[(size_t)row * D + col] = __float2half(acc[c][r] * dv);
        }
    }
}

__device__ inline void add8h(float* acc, float4 raw) {
    const __half2* hp = (const __half2*)&raw;
#pragma unroll
    for (int q = 0; q < 4; ++q) {
        float2 f = __half22float2(hp[q]);
        acc[2 * q] += f.x;
        acc[2 * q + 1] += f.y;
    }
}

// ---------------- aggregation (cheap variant; r10-proven 67.5us) ------------------
// h pre-scaled by dinv[row]; gather+add; out = relu(dinv[node]*acc + bias).
// 16 lanes x 16B cover a row; 4 groups; prefetch 8 rows/pass (32 in flight/wave).
__global__ __launch_bounds__(256) void k_agg(const __half* __restrict__ hs,
                                             const int* __restrict__ rowstart,
                                             const int* __restrict__ cnt,
                                             const int* __restrict__ csr_src,
                                             const float* __restrict__ dinv,
                                             const float* __restrict__ bias,
                                             __half* __restrict__ hout) {
    const int node = blockIdx.x * 4 + (threadIdx.x >> 6);  // NN % 4 == 0, exact grid
    const int lane = threadIdx.x & 63;
    const int g = lane >> 4;           // neighbor group 0..3
    const int f8 = (lane & 15) << 3;   // feature offset (8 halves = 16B per lane)

    float acc[8] = {};
    if (g == 0) add8h(acc, *(const float4*)&hs[(size_t)node * D + f8]);  // self-loop

    const int c = cnt[node];
    const int* __restrict__ cl = csr_src + rowstart[node];

    int t = g;
    while (t < c) {
        float4 v[8];
#pragma unroll
        for (int i = 0; i < 8; ++i) {
            int tt = t + 4 * i;
            if (tt < c) {
                int s = cl[tt];
                v[i] = *(const float4*)&hs[(size_t)s * D + f8];
            }
        }
#pragma unroll
        for (int i = 0; i < 8; ++i) {
            int tt = t + 4 * i;
            if (tt < c) add8h(acc, v[i]);
        }
        t += 32;
    }

#pragma unroll
    for (int q = 0; q < 8; ++q) {
        acc[q] += __shfl_xor(acc[q], 16);
        acc[q] += __shfl_xor(acc[q], 32);
    }

    if (g == 0) {
        const float dv = dinv[node];
        float r[8];
#pragma unroll
        for (int q = 0; q < 8; ++q) r[q] = fmaxf(fmaf(dv, acc[q], bias[f8 + q]), 0.f);
        union { float4 f; __half2 h[4]; } u;
#pragma unroll
        for (int q = 0; q < 4; ++q) u.h[q] = __floats2half2_rn(r[2 * q], r[2 * q + 1]);
        *(float4*)&hout[(size_t)node * D + f8] = u.f;
    }
}

// ---------------- output: softmax(h @ Wout + bout), fp16 h ----------------
__global__ void k_out(const __half* __restrict__ h, const float* __restrict__ Wout,
                      const float* __restrict__ bout, float* __restrict__ out, int n) {
    __shared__ float ws[D * NC];
    int tid = threadIdx.x;
    for (int i = tid; i < D * NC; i += 256) ws[i] = Wout[i];
    __syncthreads();
    int node = blockIdx.x * 32 + (tid >> 3);
    int c = tid & 7;
    if (node >= n) return;
    float acc = bout[c];
    const __half* hrow = &h[(size_t)node * D];
#pragma unroll
    for (int k8 = 0; k8 < 16; ++k8) {
        float4 raw = *(const float4*)&hrow[k8 * 8];
        const __half2* hp = (const __half2*)&raw;
#pragma unroll
        for (int q = 0; q < 4; ++q) {
            float2 f = __half22float2(hp[q]);
            int k = k8 * 8 + 2 * q;
            acc += f.x * ws[k * NC + c] + f.y * ws[(k + 1) * NC + c];
        }
    }
    float m = acc;
#pragma unroll
    for (int off = 1; off < 8; off <<= 1) m = fmaxf(m, __shfl_xor(m, off));
    float e = __expf(acc - m);
    float ssum = e;
#pragma unroll
    for (int off = 1; off < 8; off <<= 1) ssum += __shfl_xor(ssum, off);
    out[(size_t)node * NC + c] = e / ssum;
}

// ---------------- launch ----------------
extern "C" void kernel_launch(void* const* d_in, const int* in_sizes, int n_in,
                              void* d_out, int out_size, void* d_ws, size_t ws_size,
                              hipStream_t stream) {
    const float* x    = (const float*)d_in[0];
    const int*   ei   = (const int*)d_in[1];   // [2][NE]: row 0 = src, row 1 = dst
    const float* W1   = (const float*)d_in[2];
    const float* b1   = (const float*)d_in[3];
    const float* W2   = (const float*)d_in[4];
    const float* b2   = (const float*)d_in[5];
    const float* Wout = (const float*)d_in[6];
    const float* bout = (const float*)d_in[7];
    float* out = (float*)d_out;

    size_t off = 0;
    char* base = (char*)d_ws;
    auto alloc = [&](size_t bytes) -> void* {
        void* p = base + off;
        off += (bytes + 255) & ~(size_t)255;
        return p;
    };
    int*    cnt      = (int*)alloc((size_t)NN * 4);
    int*    rowstart = (int*)alloc((size_t)NN * 4);
    int*    bcursor  = (int*)alloc((size_t)NBUCK * 4);
    int*    csr      = (int*)alloc((size_t)NBUCK * BCAP * 4);  // bucket-padded
    float*  dinv     = (float*)alloc((size_t)NN * 4);
    __half* wt1      = (__half*)alloc((size_t)D * D * 2);
    __half* wt2      = (__half*)alloc((size_t)D * D * 2);
    __half* h16a     = (__half*)alloc((size_t)NN * D * 2);  // gemm out (pre-scaled)
    __half* h16f     = (__half*)alloc((size_t)NN * D * 2);  // agg1 out
    __half* h16b     = (__half*)alloc((size_t)NN * D * 2);  // agg2 out
    int*    staged   = (int*)alloc((size_t)NBUCK * BCAP * 4);
    if (off > ws_size) return;  // workspace too small; fail visibly

    const int* src = ei;
    const int* dst = ei + NE;

    hipMemsetAsync(bcursor, 0, (size_t)NBUCK * 4, stream);

    // K1: bucket scatter (391 blocks) + weight cvt (2 blocks)
    k_scat<<<NBLK_SC + 2, 256, 0, stream>>>(src, dst, bcursor, staged,
                                            W1, wt1, W2, wt2, NE);
    // K2: per-bucket CSR build -> rowstart/cnt/dinv/csr
    k_bfill<<<NBUCK, 256, 0, stream>>>(staged, bcursor, rowstart, cnt, dinv, csr);

    int gemm_grid = NN / 32;   // 3125 exactly
    int agg_grid = NN / 4;     // 25000 exactly
    // layer 1: scaled gemm -> cheap agg
    k_gemm<true><<<gemm_grid, 256, 0, stream>>>(x, wt1, dinv, h16a);
    k_agg<<<agg_grid, 256, 0, stream>>>(h16a, rowstart, cnt, csr, dinv, b1, h16f);
    // layer 2: scaled gemm -> cheap agg
    k_gemm<false><<<gemm_grid, 256, 0, stream>>>(h16f, wt2, dinv, h16a);
    k_agg<<<agg_grid, 256, 0, stream>>>(h16a, rowstart, cnt, csr, dinv, b2, h16b);
    // output projection + softmax
    k_out<<<(NN + 31) / 32, 256, 0, stream>>>(h16b, Wout, bout, out, NN);
}